// Round 13
// baseline (354.352 us; speedup 1.0000x reference)
//
#include <hip/hip_runtime.h>
#include <math.h>

// ---- weight buffer layout ----
// fp32 section (dwords 0..1232):
// W1[16][5]@0 b1@80 | W2[32][16]@96 b2@608 | W3[16][35]@640 b3@1200 | W4[16]@1216 b4@1232
// packed fp16 section (uint view at dword offset 1280):
// w1a[16]@0 | w1b[16]@16 | w1c[16]@32 | w2pk[32][8]@48 | b1f[16]@304 | b2f[32]@320
#define WTOT  1233
#define PKOFS 1280
#define PKTOT 352

// scat LDS staging capacity (edges). Bucket padded size ~8190+768, std ~90 ->
// 12288 is ~45 sigma; fallback path covers the (unreachable) overflow case.
#define SCAT_CAP 12288

typedef __fp16 h2 __attribute__((ext_vector_type(2)));
typedef __fp16 f16x8 __attribute__((ext_vector_type(8)));
typedef float f32x16 __attribute__((ext_vector_type(16)));

__device__ __forceinline__ h2 u2h(unsigned int u) { return __builtin_bit_cast(h2, u); }
__device__ __forceinline__ unsigned int h2u(h2 h) { return __builtin_bit_cast(unsigned int, h); }
#define DOT2(a, b, c) __builtin_amdgcn_fdot2((a), (b), (c), false)

__device__ __forceinline__ float softplus_f(float x) {
  return fmaxf(x, 0.f) + log1pf(expf(-fabsf(x)));
}

struct PrepArgs {
  const float* wmu[4]; const float* wrho[4]; const float* epsw[4];
  const float* bmu[4]; const float* brho[4]; const float* epsb[4];
  float* out; int* bucketCur; int* etot; int nbuck;
};

// single block 1024: sample all weights, pack fp16 section, zero bucketCur+etot
__global__ void prep_all_kernel(PrepArgs a) {
  const int wsz[4] = {80, 512, 560, 16};
  const int wof[4] = {0, 96, 640, 1216};
  const int bsz[4] = {16, 32, 16, 1};
  const int bof[4] = {80, 608, 1200, 1232};
  float* wg = a.out;
  int tid = threadIdx.x;
  if (tid < a.nbuck) a.bucketCur[tid] = 0;
  if (tid == 1023) *a.etot = 0;
#pragma unroll
  for (int l = 0; l < 4; l++) {
    for (int i = tid; i < wsz[l]; i += 1024)
      wg[wof[l] + i] = a.wmu[l][i] + softplus_f(a.wrho[l][i]) * a.epsw[l][i];
    for (int i = tid; i < bsz[l]; i += 1024)
      wg[bof[l] + i] = a.bmu[l][i] + softplus_f(a.brho[l][i]) * a.epsb[l][i];
  }
  __syncthreads();
  unsigned int* wp = (unsigned int*)(wg + PKOFS);
  int t = tid;
  if (t < 16) {
    wp[t]      = h2u(h2{(__fp16)wg[t * 5 + 0], (__fp16)wg[t * 5 + 1]});
    wp[16 + t] = h2u(h2{(__fp16)wg[t * 5 + 2], (__fp16)0.f});
    wp[32 + t] = h2u(h2{(__fp16)wg[t * 5 + 3], (__fp16)wg[t * 5 + 4]});
    ((float*)wp)[304 + t] = wg[80 + t];
  }
  if (t < 32) {
    ((float*)wp)[320 + t] = wg[608 + t];
    for (int j = 0; j < 8; j++)
      wp[48 + t * 8 + j] =
          h2u(h2{(__fp16)wg[96 + t * 16 + 2 * j], (__fp16)wg[96 + t * 16 + 2 * j + 1]});
  }
}

// per-block LDS histogram of dst buckets (bucket = dst>>8) + FUSED xpack &
// agg32-zero for this block's 256-node range (independent work, overlaps the
// histogram's memory phases; saves the separate xpack launch).
__global__ __launch_bounds__(1024) void bhist_kernel(
    const int* __restrict__ dst, int* __restrict__ bucketCur,
    const float* __restrict__ x, uint2* __restrict__ xpk,
    unsigned int* __restrict__ agg32, int E, int N, int NBUCK) {
  __shared__ int h[1024];
  int tid = threadIdx.x;
  for (int i = tid; i < NBUCK; i += 1024) h[i] = 0;
  // fused xpack (256 nodes/block)
  int nbase = blockIdx.x * 256;
  if (tid < 256) {
    int i = nbase + tid;
    if (i < N) {
      h2 a = __builtin_amdgcn_cvt_pkrtz(x[3 * i], x[3 * i + 1]);
      h2 b = __builtin_amdgcn_cvt_pkrtz(x[3 * i + 2], 0.f);
      xpk[i] = make_uint2(h2u(a), h2u(b));
    }
  }
  // fused agg32 zero (rows nbase..nbase+255, incl. sentinel row N): 8 uint4/row
  {
    uint4 z = make_uint4(0u, 0u, 0u, 0u);
    uint4* ap = (uint4*)agg32;
    size_t lim = ((size_t)N + 1) * 8;
    size_t i0 = (size_t)nbase * 8 + tid;
    if (i0 < lim) ap[i0] = z;
    size_t i1 = i0 + 1024;
    if (i1 < (size_t)(nbase + 256) * 8 && i1 < lim) ap[i1] = z;
  }
  __syncthreads();
  int base = blockIdx.x * 8192;
#pragma unroll
  for (int r = 0; r < 2; r++) {
    int e = base + r * 4096 + tid * 4;
    if (e + 3 < E) {
      int4 d4v = *(const int4*)(dst + e);
      atomicAdd(&h[d4v.x >> 8], 1);
      atomicAdd(&h[d4v.y >> 8], 1);
      atomicAdd(&h[d4v.z >> 8], 1);
      atomicAdd(&h[d4v.w >> 8], 1);
    } else {
      for (int k = 0; k < 4; k++)
        if (e + k < E) atomicAdd(&h[dst[e + k] >> 8], 1);
    }
  }
  __syncthreads();
  for (int i = tid; i < NBUCK; i += 1024) {
    int c = h[i];
    if (c) atomicAdd(&bucketCur[i], c);
  }
}

// single-block exclusive scan over NBUCK (<=1024) counts held in bucketCur;
// writes bucketOff[0..NBUCK] and re-seeds bucketCur with the exclusive offsets
__global__ __launch_bounds__(1024) void scanBk_kernel(int* __restrict__ bucketCur,
                                                      int* __restrict__ bucketOff,
                                                      int NBUCK) {
  __shared__ int wsum[16];
  __shared__ int woff[16];
  int tid = threadIdx.x, lane = tid & 63, wid = tid >> 6;
  int v = (tid < NBUCK) ? bucketCur[tid] : 0;
  int x = v;
#pragma unroll
  for (int off = 1; off < 64; off <<= 1) {
    int t = __shfl_up(x, off, 64);
    if (lane >= off) x += t;
  }
  if (lane == 63) wsum[wid] = x;
  __syncthreads();
  if (wid == 0) {
    int s = (lane < 16) ? wsum[lane] : 0;
#pragma unroll
    for (int off = 1; off < 16; off <<= 1) {
      int t = __shfl_up(s, off, 64);
      if (lane >= off) s += t;
    }
    if (lane < 16) woff[lane] = s - wsum[lane];
  }
  __syncthreads();
  int excl = woff[wid] + x - v;
  if (tid < NBUCK) {
    bucketOff[tid] = excl;
    bucketCur[tid] = excl;
    if (tid == NBUCK - 1) bucketOff[NBUCK] = excl + v;
  }
}

// partition edges into bucket regions: per-block LDS hist -> global reserve ->
// LDS-cursor append. PACKED 8B/edge record {ea, src|(dst&255)<<24} — dst's
// high bits are implied by the bucket (dst>>8 == b), src fits 24 bits.
// 8192 edges/block (R3 lesson: occupancy >> chunk depth); 256-node buckets.
__global__ __launch_bounds__(1024) void part_kernel(
    const int* __restrict__ src, const int* __restrict__ dst,
    const float2* __restrict__ ea, int* __restrict__ bucketCur,
    uint2* __restrict__ brec8, int E, int NBUCK) {
  __shared__ int h[1024];
  int tid = threadIdx.x;
  for (int i = tid; i < NBUCK; i += 1024) h[i] = 0;
  __syncthreads();
  int base = blockIdx.x * 8192;
  int d[8], s[8];
  unsigned int a[8];
  bool v[8];
#pragma unroll
  for (int j = 0; j < 8; j++) {
    int e = base + j * 1024 + tid;
    v[j] = e < E;
    if (v[j]) {
      d[j] = dst[e];
      s[j] = src[e];
      float2 t = ea[e];
      a[j] = h2u(__builtin_amdgcn_cvt_pkrtz(t.x, t.y));
      atomicAdd(&h[d[j] >> 8], 1);
    }
  }
  __syncthreads();
  for (int i = tid; i < NBUCK; i += 1024) {
    int c = h[i];
    h[i] = c ? atomicAdd(&bucketCur[i], c) : 0;
  }
  __syncthreads();
#pragma unroll
  for (int j = 0; j < 8; j++) {
    if (v[j]) {
      int pos = atomicAdd(&h[d[j] >> 8], 1);
      brec8[pos] = make_uint2(a[j], (unsigned int)s[j] | ((unsigned int)(d[j] & 255) << 24));
    }
  }
}

// scat (R17): LDS-STAGED per-bucket build. hist -> padded scan -> ONE
// atomicAdd(etot) reserves a 4-aligned region -> scatter into a 96KB LDS
// stage -> pad-fill in LDS -> COALESCED uint4 copy-out. Fallback to direct
// global scatter if a bucket exceeds SCAT_CAP (statistically unreachable).
__global__ __launch_bounds__(1024) void scat_kernel(
    const uint2* __restrict__ brec8, const int* __restrict__ bucketOff,
    int* __restrict__ etot, uint2* __restrict__ se8, unsigned int* __restrict__ d4,
    int N) {
  __shared__ int cnt[256];     // count -> running cursor
  __shared__ int sstart[256];  // start positions (LDS- or global-relative)
  __shared__ int wsum[4];
  __shared__ int woff[4];
  __shared__ int sbase;
  __shared__ int ptot;
  __shared__ __align__(16) uint2 stage[SCAT_CAP];      // 96KB
  __shared__ unsigned int staged4[SCAT_CAP / 4];       // 12KB
  int b = blockIdx.x, tid = threadIdx.x;
  int lane = tid & 63, wid = tid >> 6;
  if (tid < 256) cnt[tid] = 0;
  __syncthreads();
  int e0 = bucketOff[b], e1 = bucketOff[b + 1];
  for (int i = e0 + tid; i < e1; i += 1024) atomicAdd(&cnt[brec8[i].y >> 24], 1);
  __syncthreads();
  // padded exclusive scan over the 256 counts (threads 0..255 = 4 waves)
  int v = 0;
  if (tid < 256) v = (cnt[tid] + 3) & ~3;
  int x = v;
#pragma unroll
  for (int off = 1; off < 64; off <<= 1) {
    int t = __shfl_up(x, off, 64);
    if (lane >= off) x += t;
  }
  if (tid < 256 && lane == 63) wsum[wid] = x;
  __syncthreads();
  if (wid == 0 && lane < 4) {
    int s = wsum[lane];
#pragma unroll
    for (int off = 1; off < 4; off <<= 1) {
      int t = __shfl_up(s, off, 64);
      if (lane >= off) s += t;
    }
    woff[lane] = s - wsum[lane];
    if (lane == 3) { ptot = s; sbase = atomicAdd(etot, s); }  // s = padded total
  }
  __syncthreads();
  int total = ptot;
  if (total <= SCAT_CAP) {
    // ---- LDS-staged path ----
    if (tid < 256) {
      int start = woff[wid] + x - v;   // LDS-relative
      sstart[tid] = start;
      cnt[tid] = start;
    }
    __syncthreads();
    for (int i = e0 + tid; i < e1; i += 1024) {
      uint2 t = brec8[i];
      int pos = atomicAdd(&cnt[t.y >> 24], 1);
      stage[pos] = make_uint2(t.y & 0x00FFFFFFu, t.x);
    }
    __syncthreads();
    if (tid < 256) {
      int start = sstart[tid];
      int endR = cnt[tid];                          // start + real deg
      int endP = start + ((endR - start + 3) & ~3); // start + padded deg
      if (endR > start) {
        uint2 rep = stage[start];
        for (int k = endR; k < endP; k++) stage[k] = rep;
        unsigned int node = (unsigned int)(b * 256 + tid);
        for (int k = start; k < endP; k += 4) staged4[k >> 2] = node;
      }
    }
    __syncthreads();
    int base = sbase;                 // 4-aligned => 32B-aligned uint4 dst
    uint4* dstp = (uint4*)(se8 + base);
    const uint4* srcp = (const uint4*)stage;
    int n4 = total >> 1;              // total % 4 == 0
    for (int i = tid; i < n4; i += 1024) dstp[i] = srcp[i];
    unsigned int* d4p = d4 + (base >> 2);
    int nd = total >> 2;
    for (int i = tid; i < nd; i += 1024) d4p[i] = staged4[i];
  } else {
    // ---- fallback: direct global scatter (old R16 path) ----
    if (tid < 256) {
      int start = sbase + woff[wid] + x - v;
      sstart[tid] = start;
      cnt[tid] = start;
    }
    __syncthreads();
    for (int i = e0 + tid; i < e1; i += 1024) {
      uint2 t = brec8[i];
      int pos = atomicAdd(&cnt[t.y >> 24], 1);
      se8[pos] = make_uint2(t.y & 0x00FFFFFFu, t.x);
    }
    __syncthreads();
    if (tid < 256) {
      unsigned int node = (unsigned int)(b * 256 + tid);
      int start = sstart[tid];
      int endR = cnt[tid];
      int endP = start + ((endR - start + 3) & ~3);
      if (endR > start) {
        uint2 rep = se8[start];
        for (int k = endR; k < endP; k++) se8[k] = rep;
        for (int k = start; k < endP; k += 4) d4[k >> 2] = node;
      }
    }
  }
}

// edge kernel (R19): per-wave schedule IDENTICAL to R10's proven config
// (1 edge/lane, 64-edge window, wave-private LDS slice, 2x mfma_32x32x16,
// setprio, tagged atomicMax). ONE change: 1024-thread blocks (16 wave-slots,
// 48KB LDS) instead of 256-thread — 4x fewer blocks (3.2K vs 12.9K) for the
// command processor to dispatch. Theory: measured 42% occupancy with NO
// resource limit (VGPR 44, LDS fits, grid huge) = dispatch-rate-limited by
// 1.3us block lifetimes; bigger blocks amortize dispatch. Wave cap unchanged
// (2 blocks/CU x 16 waves = 32). R5/R11 changed per-WAVE structure and lost;
// this changes only launch geometry.
__global__ __launch_bounds__(1024) void edge_kernel(
    const uint2* __restrict__ xpk, const uint2* __restrict__ se8,
    const unsigned int* __restrict__ d4, unsigned int* __restrict__ agg32,
    const float* __restrict__ wg, const int* __restrict__ pEtot,
    unsigned int tag, int N) {
  __shared__ __align__(16) unsigned int lds[16][64][12];  // 48KB, wave-private slices
  const unsigned int* wp = (const unsigned int*)(wg + PKOFS);
  const float* bf = (const float*)wp;
  const int Etot = *pEtot;
  if (blockIdx.x * 1024 >= Etot) return;  // whole-block tail skip
  const int tid = threadIdx.x;
  const int lane = tid & 63;
  const int wslot = tid >> 6;
  const int e = blockIdx.x * 1024 + tid;

  bool vld = e < Etot;
  uint2 se = vld ? se8[e] : make_uint2(0u, 0u);
  int d = vld ? (int)d4[e >> 2] : N;      // sentinel run (skipped at atomic)
  uint2 xs = xpk[se.x];

  // ---- layer1: 5->16 fp16 dot2, packed relu output m1[8] (16 fp16) ----
  h2 p01 = u2h(xs.x), p2v = u2h(xs.y), pea = u2h(se.y);
  unsigned int m1[8];
#pragma unroll
  for (int p = 0; p < 8; p++) {
    const int oA = 2 * p, oB = 2 * p + 1;
    float sA = DOT2(p01, u2h(wp[oA]),
                DOT2(p2v, u2h(wp[16 + oA]),
                DOT2(pea, u2h(wp[32 + oA]), bf[304 + oA])));
    float sB = DOT2(p01, u2h(wp[oB]),
                DOT2(p2v, u2h(wp[16 + oB]),
                DOT2(pea, u2h(wp[32 + oB]), bf[304 + oB])));
    m1[p] = h2u(__builtin_amdgcn_cvt_pkrtz(fmaxf(sA, 0.f), fmaxf(sB, 0.f)));
  }

  // ---- stage m1 into wave-private LDS slice (stride 12 dwords) ----
  uint4* rowp = (uint4*)&lds[wslot][lane][0];
  rowp[0] = make_uint4(m1[0], m1[1], m1[2], m1[3]);
  rowp[1] = make_uint4(m1[4], m1[5], m1[6], m1[7]);
  // wave-private tile: only need LDS write-drain, not a block barrier
  asm volatile("s_waitcnt lgkmcnt(0)" ::: "memory");
  __builtin_amdgcn_sched_barrier(0);

  const int col = lane & 31;   // output feature (D col)
  const int h = lane >> 5;     // k-half / row-half selector
  f16x8 bfrag = __builtin_bit_cast(f16x8, *(const uint4*)&wp[48 + col * 8 + 4 * h]);
  float bias = bf[320 + col];
  f32x16 cini;
#pragma unroll
  for (int i = 0; i < 16; i++) cini[i] = bias;

  __builtin_amdgcn_s_setprio(1);
  f16x8 a0 = __builtin_bit_cast(f16x8, *(const uint4*)&lds[wslot][col][4 * h]);
  f16x8 a1 = __builtin_bit_cast(f16x8, *(const uint4*)&lds[wslot][32 + col][4 * h]);
  f32x16 acc0 = __builtin_amdgcn_mfma_f32_32x32x16_f16(a0, bfrag, cini, 0, 0, 0);
  f32x16 acc1 = __builtin_amdgcn_mfma_f32_32x32x16_f16(a1, bfrag, cini, 0, 0, 0);

  // ---- per-4-edge-block max (relu folded). lane holds blocks 8g+2q+h ----
  float bm[2][4];
#pragma unroll
  for (int q = 0; q < 4; q++) {
    bm[0][q] = fmaxf(fmaxf(acc0[4 * q], acc0[4 * q + 1]),
                     fmaxf(acc0[4 * q + 2], fmaxf(acc0[4 * q + 3], 0.f)));
    bm[1][q] = fmaxf(fmaxf(acc1[4 * q], acc1[4 * q + 1]),
                     fmaxf(acc1[4 * q + 2], fmaxf(acc1[4 * q + 3], 0.f)));
  }
  __builtin_amdgcn_s_setprio(0);

  // ---- run structure: heads only at 4-aligned lanes (padded scatter) ----
  int dp4 = __shfl_up(d, 4, 64);
  bool isHead = ((lane & 3) == 0) && (lane == 0 || d != dp4);
  unsigned long long hm = __ballot(isHead);

  unsigned long long rem = hm;
  while (rem) {
    int a = (int)__builtin_ctzll(rem);
    rem &= rem - 1;
    int b = rem ? (int)__builtin_ctzll(rem) : 64;
    int rd = __shfl(d, a, 64);
    int A = a >> 2, B = b >> 2;   // block range of this run
    float mx = 0.f;
#pragma unroll
    for (int g = 0; g < 2; g++) {
#pragma unroll
      for (int q = 0; q < 4; q++) {
        int blk = 8 * g + 2 * q + h;
        bool in = (blk >= A) && (blk < B);
        mx = fmaxf(mx, in ? bm[g][q] : 0.f);
      }
    }
    mx = fmaxf(mx, __shfl_xor(mx, 32, 64));
    if (lane < 32 && rd < N) {
      unsigned int bits = __float_as_uint(mx);
      atomicMax(agg32 + (size_t)rd * 32 + col, (tag << 30) | (bits >> 1));
    }
  }
}

// node-parallel: read agg row, TAG-decode (no zeroing pass), node MLP.
__global__ __launch_bounds__(256) void node_kernel(
    const float* __restrict__ x, const float* __restrict__ cin,
    float* __restrict__ cout, uint2* __restrict__ xpk,
    float* __restrict__ outFinal, const unsigned int* __restrict__ agg32,
    const float* __restrict__ wg, unsigned int tag, int n) {
  int nid = blockIdx.x * blockDim.x + threadIdx.x;
  if (nid >= n) return;
  const uint4* ap = (const uint4*)(agg32 + (size_t)nid * 32);
  uint4 q[8];
#pragma unroll
  for (int i = 0; i < 8; i++) q[i] = ap[i];
  float av[32];
#pragma unroll
  for (int i = 0; i < 8; i++) {
    unsigned int w[4] = {q[i].x, q[i].y, q[i].z, q[i].w};
#pragma unroll
    for (int j = 0; j < 4; j++) {
      unsigned int u = ((w[j] >> 30) == tag) ? ((w[j] & 0x3FFFFFFFu) << 1) : 0u;
      av[4 * i + j] = __uint_as_float(u);
    }
  }
  float x0 = x[3 * nid], x1 = x[3 * nid + 1];
  float x2 = cin ? cin[nid] : x[3 * nid + 2];
  float h[16];
#pragma unroll
  for (int o = 0; o < 16; o++) {
    float sa = wg[1200 + o];
    sa = fmaf(wg[640 + o * 35 + 0], x0, sa);
    sa = fmaf(wg[640 + o * 35 + 1], x1, sa);
    sa = fmaf(wg[640 + o * 35 + 2], x2, sa);
#pragma unroll
    for (int k = 0; k < 32; k++) sa = fmaf(wg[640 + o * 35 + 3 + k], av[k], sa);
    h[o] = fmaxf(sa, 0.f);
  }
  float z4 = wg[1232];
#pragma unroll
  for (int k = 0; k < 16; k++) z4 = fmaf(wg[1216 + k], h[k], z4);
  float comb = 1.f / (1.f + expf(-z4));
  cout[nid] = comb;
  ((unsigned int*)xpk)[2 * nid + 1] = h2u(__builtin_amdgcn_cvt_pkrtz(comb, 0.f));
  if (outFinal) {
    outFinal[3 * nid] = x0;
    outFinal[3 * nid + 1] = x1;
    outFinal[3 * nid + 2] = comb;
  }
}

extern "C" void kernel_launch(void* const* d_in, const int* in_sizes, int n_in,
                              void* d_out, int out_size, void* d_ws, size_t ws_size,
                              hipStream_t stream) {
  const float* x = (const float*)d_in[0];
  const float* ea = (const float*)d_in[1];
  const int* eidx = (const int*)d_in[2];
  const int N = in_sizes[0] / 3;
  const int E = in_sizes[1] / 2;
  const int* src = eidx;
  const int* dst = eidx + E;
  const int NBUCK = (N + 255) >> 8;  // dst buckets, 256 nodes each
  const int EP = E + 3 * N;          // padded-edge upper bound (actual in *etot)

  // ---- workspace carve-up ----
  char* p = (char*)d_ws;
  size_t off = 0;
  auto alloc = [&](size_t bytes) -> char* {
    char* r = p + off;
    off = (off + bytes + 255) & ~(size_t)255;
    return r;
  };
  float* wbuf = (float*)alloc((size_t)(PKOFS + PKTOT) * 4);
  int* bucketOff = (int*)alloc(((size_t)NBUCK + 1) * 4);
  int* bucketCur = (int*)alloc((size_t)NBUCK * 4);
  int* etot = (int*)alloc(4);
  uint2* se8 = (uint2*)alloc((size_t)EP * 8);            // {src, ea} per edge
  unsigned int* d4 = (unsigned int*)alloc(((size_t)(EP + 3) / 4 + 1) * 4);
  // agg32/xpk OUTSIDE the union: bhist initializes them while brec8 is live.
  unsigned int* agg32 = (unsigned int*)alloc(((size_t)N + 1) * 32 * 4);
  uint2* xpk = (uint2*)alloc((size_t)N * 8);
  // UNION region: build-phase brec8 (8B/edge) aliased with iteration-phase
  // bufA/bufB (brec8 dead after scat).
  char* uni = alloc((size_t)E * 8);
  uint2* brec8 = (uint2*)uni;
  float* bufA = (float*)uni;
  float* bufB = (float*)(uni + (((size_t)N * 4 + 255) & ~(size_t)255));
  (void)ws_size;

  PrepArgs pa;
  for (int l = 0; l < 4; l++) {
    pa.wmu[l] = (const float*)d_in[3 + 6 * l + 0];
    pa.wrho[l] = (const float*)d_in[3 + 6 * l + 1];
    pa.bmu[l] = (const float*)d_in[3 + 6 * l + 2];
    pa.brho[l] = (const float*)d_in[3 + 6 * l + 3];
    pa.epsw[l] = (const float*)d_in[3 + 6 * l + 4];
    pa.epsb[l] = (const float*)d_in[3 + 6 * l + 5];
  }
  pa.out = wbuf;
  pa.bucketCur = bucketCur;
  pa.etot = etot;
  pa.nbuck = NBUCK;

  const int TB = 256;
  auto blocks = [&](int n) { return dim3((n + TB - 1) / TB); };

  prep_all_kernel<<<dim3(1), dim3(1024), 0, stream>>>(pa);
  {
    int gb = (E + 8191) / 8192;
    int gn = (N + 255) / 256;
    int g = gb > gn ? gb : gn;
    bhist_kernel<<<dim3(g), dim3(1024), 0, stream>>>(dst, bucketCur, x, xpk, agg32,
                                                     E, N, NBUCK);
  }
  scanBk_kernel<<<dim3(1), dim3(1024), 0, stream>>>(bucketCur, bucketOff, NBUCK);
  part_kernel<<<dim3((E + 8191) / 8192), dim3(1024), 0, stream>>>(
      src, dst, (const float2*)ea, bucketCur, brec8, E, NBUCK);
  scat_kernel<<<dim3(NBUCK), dim3(1024), 0, stream>>>(brec8, bucketOff, etot, se8, d4, N);

  float* outp = (float*)d_out;
  const int ebp = (EP + 1023) / 1024;   // 1024-thread edge blocks (R19)
  // iter 1
  edge_kernel<<<dim3(ebp), dim3(1024), 0, stream>>>(xpk, se8, d4, agg32, wbuf, etot, 1u, N);
  node_kernel<<<blocks(N), dim3(TB), 0, stream>>>(x, nullptr, bufA, xpk, nullptr,
                                                  agg32, wbuf, 1u, N);
  // iter 2
  edge_kernel<<<dim3(ebp), dim3(1024), 0, stream>>>(xpk, se8, d4, agg32, wbuf, etot, 2u, N);
  node_kernel<<<blocks(N), dim3(TB), 0, stream>>>(x, bufA, bufB, xpk, nullptr,
                                                  agg32, wbuf, 2u, N);
  // iter 3
  edge_kernel<<<dim3(ebp), dim3(1024), 0, stream>>>(xpk, se8, d4, agg32, wbuf, etot, 3u, N);
  node_kernel<<<blocks(N), dim3(TB), 0, stream>>>(x, bufB, bufA, xpk, outp,
                                                  agg32, wbuf, 3u, N);
}

// Round 14
// 323.582 us; speedup vs baseline: 1.0951x; 1.0951x over previous
//
#include <hip/hip_runtime.h>
#include <math.h>

// ---- weight buffer layout ----
// fp32 section (dwords 0..1232):
// W1[16][5]@0 b1@80 | W2[32][16]@96 b2@608 | W3[16][35]@640 b3@1200 | W4[16]@1216 b4@1232
// packed fp16 section (uint view at dword offset 1280):
// w1a[16]@0 | w1b[16]@16 | w1c[16]@32 | w2pk[32][8]@48 | b1f[16]@304 | b2f[32]@320
#define WTOT  1233
#define PKOFS 1280
#define PKTOT 352

// scat LDS staging capacity (edges). Bucket padded size ~8190+768, std ~90 ->
// 12288 is ~45 sigma; fallback path covers the (unreachable) overflow case.
#define SCAT_CAP 12288

typedef __fp16 h2 __attribute__((ext_vector_type(2)));
typedef __fp16 f16x8 __attribute__((ext_vector_type(8)));
typedef float f32x16 __attribute__((ext_vector_type(16)));

__device__ __forceinline__ h2 u2h(unsigned int u) { return __builtin_bit_cast(h2, u); }
__device__ __forceinline__ unsigned int h2u(h2 h) { return __builtin_bit_cast(unsigned int, h); }
#define DOT2(a, b, c) __builtin_amdgcn_fdot2((a), (b), (c), false)

__device__ __forceinline__ float softplus_f(float x) {
  return fmaxf(x, 0.f) + log1pf(expf(-fabsf(x)));
}

struct PrepArgs {
  const float* wmu[4]; const float* wrho[4]; const float* epsw[4];
  const float* bmu[4]; const float* brho[4]; const float* epsb[4];
  float* out; int* bucketCur; int* etot; int nbuck;
};

// single block 1024: sample all weights, pack fp16 section, zero bucketCur+etot
__global__ void prep_all_kernel(PrepArgs a) {
  const int wsz[4] = {80, 512, 560, 16};
  const int wof[4] = {0, 96, 640, 1216};
  const int bsz[4] = {16, 32, 16, 1};
  const int bof[4] = {80, 608, 1200, 1232};
  float* wg = a.out;
  int tid = threadIdx.x;
  if (tid < a.nbuck) a.bucketCur[tid] = 0;
  if (tid == 1023) *a.etot = 0;
#pragma unroll
  for (int l = 0; l < 4; l++) {
    for (int i = tid; i < wsz[l]; i += 1024)
      wg[wof[l] + i] = a.wmu[l][i] + softplus_f(a.wrho[l][i]) * a.epsw[l][i];
    for (int i = tid; i < bsz[l]; i += 1024)
      wg[bof[l] + i] = a.bmu[l][i] + softplus_f(a.brho[l][i]) * a.epsb[l][i];
  }
  __syncthreads();
  unsigned int* wp = (unsigned int*)(wg + PKOFS);
  int t = tid;
  if (t < 16) {
    wp[t]      = h2u(h2{(__fp16)wg[t * 5 + 0], (__fp16)wg[t * 5 + 1]});
    wp[16 + t] = h2u(h2{(__fp16)wg[t * 5 + 2], (__fp16)0.f});
    wp[32 + t] = h2u(h2{(__fp16)wg[t * 5 + 3], (__fp16)wg[t * 5 + 4]});
    ((float*)wp)[304 + t] = wg[80 + t];
  }
  if (t < 32) {
    ((float*)wp)[320 + t] = wg[608 + t];
    for (int j = 0; j < 8; j++)
      wp[48 + t * 8 + j] =
          h2u(h2{(__fp16)wg[96 + t * 16 + 2 * j], (__fp16)wg[96 + t * 16 + 2 * j + 1]});
  }
}

// per-block LDS histogram of dst buckets (bucket = dst>>8) + FUSED xpack &
// agg32-zero for this block's 256-node range (independent work, overlaps the
// histogram's memory phases; saves the separate xpack launch).
__global__ __launch_bounds__(1024) void bhist_kernel(
    const int* __restrict__ dst, int* __restrict__ bucketCur,
    const float* __restrict__ x, uint2* __restrict__ xpk,
    unsigned int* __restrict__ agg32, int E, int N, int NBUCK) {
  __shared__ int h[1024];
  int tid = threadIdx.x;
  for (int i = tid; i < NBUCK; i += 1024) h[i] = 0;
  // fused xpack (256 nodes/block)
  int nbase = blockIdx.x * 256;
  if (tid < 256) {
    int i = nbase + tid;
    if (i < N) {
      h2 a = __builtin_amdgcn_cvt_pkrtz(x[3 * i], x[3 * i + 1]);
      h2 b = __builtin_amdgcn_cvt_pkrtz(x[3 * i + 2], 0.f);
      xpk[i] = make_uint2(h2u(a), h2u(b));
    }
  }
  // fused agg32 zero (rows nbase..nbase+255, incl. sentinel row N): 8 uint4/row
  {
    uint4 z = make_uint4(0u, 0u, 0u, 0u);
    uint4* ap = (uint4*)agg32;
    size_t lim = ((size_t)N + 1) * 8;
    size_t i0 = (size_t)nbase * 8 + tid;
    if (i0 < lim) ap[i0] = z;
    size_t i1 = i0 + 1024;
    if (i1 < (size_t)(nbase + 256) * 8 && i1 < lim) ap[i1] = z;
  }
  __syncthreads();
  int base = blockIdx.x * 8192;
#pragma unroll
  for (int r = 0; r < 2; r++) {
    int e = base + r * 4096 + tid * 4;
    if (e + 3 < E) {
      int4 d4v = *(const int4*)(dst + e);
      atomicAdd(&h[d4v.x >> 8], 1);
      atomicAdd(&h[d4v.y >> 8], 1);
      atomicAdd(&h[d4v.z >> 8], 1);
      atomicAdd(&h[d4v.w >> 8], 1);
    } else {
      for (int k = 0; k < 4; k++)
        if (e + k < E) atomicAdd(&h[dst[e + k] >> 8], 1);
    }
  }
  __syncthreads();
  for (int i = tid; i < NBUCK; i += 1024) {
    int c = h[i];
    if (c) atomicAdd(&bucketCur[i], c);
  }
}

// single-block exclusive scan over NBUCK (<=1024) counts held in bucketCur;
// writes bucketOff[0..NBUCK] and re-seeds bucketCur with the exclusive offsets
__global__ __launch_bounds__(1024) void scanBk_kernel(int* __restrict__ bucketCur,
                                                      int* __restrict__ bucketOff,
                                                      int NBUCK) {
  __shared__ int wsum[16];
  __shared__ int woff[16];
  int tid = threadIdx.x, lane = tid & 63, wid = tid >> 6;
  int v = (tid < NBUCK) ? bucketCur[tid] : 0;
  int x = v;
#pragma unroll
  for (int off = 1; off < 64; off <<= 1) {
    int t = __shfl_up(x, off, 64);
    if (lane >= off) x += t;
  }
  if (lane == 63) wsum[wid] = x;
  __syncthreads();
  if (wid == 0) {
    int s = (lane < 16) ? wsum[lane] : 0;
#pragma unroll
    for (int off = 1; off < 16; off <<= 1) {
      int t = __shfl_up(s, off, 64);
      if (lane >= off) s += t;
    }
    if (lane < 16) woff[lane] = s - wsum[lane];
  }
  __syncthreads();
  int excl = woff[wid] + x - v;
  if (tid < NBUCK) {
    bucketOff[tid] = excl;
    bucketCur[tid] = excl;
    if (tid == NBUCK - 1) bucketOff[NBUCK] = excl + v;
  }
}

// partition edges into bucket regions: per-block LDS hist -> global reserve ->
// LDS-cursor append. PACKED 8B/edge record {ea, src|(dst&255)<<24} — dst's
// high bits are implied by the bucket (dst>>8 == b), src fits 24 bits.
// 8192 edges/block (R3 lesson: occupancy >> chunk depth); 256-node buckets.
__global__ __launch_bounds__(1024) void part_kernel(
    const int* __restrict__ src, const int* __restrict__ dst,
    const float2* __restrict__ ea, int* __restrict__ bucketCur,
    uint2* __restrict__ brec8, int E, int NBUCK) {
  __shared__ int h[1024];
  int tid = threadIdx.x;
  for (int i = tid; i < NBUCK; i += 1024) h[i] = 0;
  __syncthreads();
  int base = blockIdx.x * 8192;
  int d[8], s[8];
  unsigned int a[8];
  bool v[8];
#pragma unroll
  for (int j = 0; j < 8; j++) {
    int e = base + j * 1024 + tid;
    v[j] = e < E;
    if (v[j]) {
      d[j] = dst[e];
      s[j] = src[e];
      float2 t = ea[e];
      a[j] = h2u(__builtin_amdgcn_cvt_pkrtz(t.x, t.y));
      atomicAdd(&h[d[j] >> 8], 1);
    }
  }
  __syncthreads();
  for (int i = tid; i < NBUCK; i += 1024) {
    int c = h[i];
    h[i] = c ? atomicAdd(&bucketCur[i], c) : 0;
  }
  __syncthreads();
#pragma unroll
  for (int j = 0; j < 8; j++) {
    if (v[j]) {
      int pos = atomicAdd(&h[d[j] >> 8], 1);
      brec8[pos] = make_uint2(a[j], (unsigned int)s[j] | ((unsigned int)(d[j] & 255) << 24));
    }
  }
}

// scat (R17): LDS-STAGED per-bucket build. hist -> padded scan -> ONE
// atomicAdd(etot) reserves a 4-aligned region -> scatter into a 96KB LDS
// stage -> pad-fill in LDS -> COALESCED uint4 copy-out. Fallback to direct
// global scatter if a bucket exceeds SCAT_CAP (statistically unreachable).
__global__ __launch_bounds__(1024) void scat_kernel(
    const uint2* __restrict__ brec8, const int* __restrict__ bucketOff,
    int* __restrict__ etot, uint2* __restrict__ se8, unsigned int* __restrict__ d4,
    int N) {
  __shared__ int cnt[256];     // count -> running cursor
  __shared__ int sstart[256];  // start positions (LDS- or global-relative)
  __shared__ int wsum[4];
  __shared__ int woff[4];
  __shared__ int sbase;
  __shared__ int ptot;
  __shared__ __align__(16) uint2 stage[SCAT_CAP];      // 96KB
  __shared__ unsigned int staged4[SCAT_CAP / 4];       // 12KB
  int b = blockIdx.x, tid = threadIdx.x;
  int lane = tid & 63, wid = tid >> 6;
  if (tid < 256) cnt[tid] = 0;
  __syncthreads();
  int e0 = bucketOff[b], e1 = bucketOff[b + 1];
  for (int i = e0 + tid; i < e1; i += 1024) atomicAdd(&cnt[brec8[i].y >> 24], 1);
  __syncthreads();
  // padded exclusive scan over the 256 counts (threads 0..255 = 4 waves)
  int v = 0;
  if (tid < 256) v = (cnt[tid] + 3) & ~3;
  int x = v;
#pragma unroll
  for (int off = 1; off < 64; off <<= 1) {
    int t = __shfl_up(x, off, 64);
    if (lane >= off) x += t;
  }
  if (tid < 256 && lane == 63) wsum[wid] = x;
  __syncthreads();
  if (wid == 0 && lane < 4) {
    int s = wsum[lane];
#pragma unroll
    for (int off = 1; off < 4; off <<= 1) {
      int t = __shfl_up(s, off, 64);
      if (lane >= off) s += t;
    }
    woff[lane] = s - wsum[lane];
    if (lane == 3) { ptot = s; sbase = atomicAdd(etot, s); }  // s = padded total
  }
  __syncthreads();
  int total = ptot;
  if (total <= SCAT_CAP) {
    // ---- LDS-staged path ----
    if (tid < 256) {
      int start = woff[wid] + x - v;   // LDS-relative
      sstart[tid] = start;
      cnt[tid] = start;
    }
    __syncthreads();
    for (int i = e0 + tid; i < e1; i += 1024) {
      uint2 t = brec8[i];
      int pos = atomicAdd(&cnt[t.y >> 24], 1);
      stage[pos] = make_uint2(t.y & 0x00FFFFFFu, t.x);
    }
    __syncthreads();
    if (tid < 256) {
      int start = sstart[tid];
      int endR = cnt[tid];                          // start + real deg
      int endP = start + ((endR - start + 3) & ~3); // start + padded deg
      if (endR > start) {
        uint2 rep = stage[start];
        for (int k = endR; k < endP; k++) stage[k] = rep;
        unsigned int node = (unsigned int)(b * 256 + tid);
        for (int k = start; k < endP; k += 4) staged4[k >> 2] = node;
      }
    }
    __syncthreads();
    int base = sbase;                 // 4-aligned => 32B-aligned uint4 dst
    uint4* dstp = (uint4*)(se8 + base);
    const uint4* srcp = (const uint4*)stage;
    int n4 = total >> 1;              // total % 4 == 0
    for (int i = tid; i < n4; i += 1024) dstp[i] = srcp[i];
    unsigned int* d4p = d4 + (base >> 2);
    int nd = total >> 2;
    for (int i = tid; i < nd; i += 1024) d4p[i] = staged4[i];
  } else {
    // ---- fallback: direct global scatter (old R16 path) ----
    if (tid < 256) {
      int start = sbase + woff[wid] + x - v;
      sstart[tid] = start;
      cnt[tid] = start;
    }
    __syncthreads();
    for (int i = e0 + tid; i < e1; i += 1024) {
      uint2 t = brec8[i];
      int pos = atomicAdd(&cnt[t.y >> 24], 1);
      se8[pos] = make_uint2(t.y & 0x00FFFFFFu, t.x);
    }
    __syncthreads();
    if (tid < 256) {
      unsigned int node = (unsigned int)(b * 256 + tid);
      int start = sstart[tid];
      int endR = cnt[tid];
      int endP = start + ((endR - start + 3) & ~3);
      if (endR > start) {
        uint2 rep = se8[start];
        for (int k = endR; k < endP; k++) se8[k] = rep;
        for (int k = start; k < endP; k += 4) d4[k >> 2] = node;
      }
    }
  }
}

// edge kernel (R12 config — CONFIRMED local optimum): 1 edge/lane, 64-edge
// window, one wave per window, 256-thread blocks. Three structural attempts
// all regressed against this: R5 (2 edges/lane: VGPR 72 > 64-cliff), R11
// (grid-stride+prefetch: serialized windows the scheduler previously swapped
// freely), R13 (1024-thread blocks: 16-wave completion granularity holds
// LDS+slots hostage on tail waves). This kernel lives on fine-grained TLP.
// Stream: se8 (8B/edge) + d4 (1 dword per 4-edge block). Layer1 5->16 fp16
// dot2; m1 via wave-private LDS tile; layer2 16->32 via TWO
// mfma_f32_32x32x16_f16 in s_setprio(1) (independent waves — attn-like regime).
// agg writes ITERATION-TAGGED: (tag<<30)|(f32bits>>1) => no per-iter zeroing.
__global__ __launch_bounds__(256) void edge_kernel(
    const uint2* __restrict__ xpk, const uint2* __restrict__ se8,
    const unsigned int* __restrict__ d4, unsigned int* __restrict__ agg32,
    const float* __restrict__ wg, const int* __restrict__ pEtot,
    unsigned int tag, int N) {
  __shared__ __align__(16) unsigned int lds[4][64][12];  // 48B stride/edge row
  const unsigned int* wp = (const unsigned int*)(wg + PKOFS);
  const float* bf = (const float*)wp;
  const int Etot = *pEtot;
  if (blockIdx.x * 256 >= Etot) return;   // whole-block tail skip
  const int tid = threadIdx.x;
  const int lane = tid & 63;
  const int wslot = tid >> 6;
  const int e = blockIdx.x * 256 + tid;

  bool vld = e < Etot;
  uint2 se = vld ? se8[e] : make_uint2(0u, 0u);
  int d = vld ? (int)d4[e >> 2] : N;      // sentinel run (skipped at atomic)
  uint2 xs = xpk[se.x];

  // ---- layer1: 5->16 fp16 dot2, packed relu output m1[8] (16 fp16) ----
  h2 p01 = u2h(xs.x), p2v = u2h(xs.y), pea = u2h(se.y);
  unsigned int m1[8];
#pragma unroll
  for (int p = 0; p < 8; p++) {
    const int oA = 2 * p, oB = 2 * p + 1;
    float sA = DOT2(p01, u2h(wp[oA]),
                DOT2(p2v, u2h(wp[16 + oA]),
                DOT2(pea, u2h(wp[32 + oA]), bf[304 + oA])));
    float sB = DOT2(p01, u2h(wp[oB]),
                DOT2(p2v, u2h(wp[16 + oB]),
                DOT2(pea, u2h(wp[32 + oB]), bf[304 + oB])));
    m1[p] = h2u(__builtin_amdgcn_cvt_pkrtz(fmaxf(sA, 0.f), fmaxf(sB, 0.f)));
  }

  // ---- stage m1 into wave-private LDS slice (stride 12 dwords) ----
  uint4* rowp = (uint4*)&lds[wslot][lane][0];
  rowp[0] = make_uint4(m1[0], m1[1], m1[2], m1[3]);
  rowp[1] = make_uint4(m1[4], m1[5], m1[6], m1[7]);
  // wave-private tile: only need LDS write-drain, not a block barrier
  asm volatile("s_waitcnt lgkmcnt(0)" ::: "memory");
  __builtin_amdgcn_sched_barrier(0);

  const int col = lane & 31;   // output feature (D col)
  const int h = lane >> 5;     // k-half / row-half selector
  f16x8 bfrag = __builtin_bit_cast(f16x8, *(const uint4*)&wp[48 + col * 8 + 4 * h]);
  float bias = bf[320 + col];
  f32x16 cini;
#pragma unroll
  for (int i = 0; i < 16; i++) cini[i] = bias;

  __builtin_amdgcn_s_setprio(1);
  f16x8 a0 = __builtin_bit_cast(f16x8, *(const uint4*)&lds[wslot][col][4 * h]);
  f16x8 a1 = __builtin_bit_cast(f16x8, *(const uint4*)&lds[wslot][32 + col][4 * h]);
  f32x16 acc0 = __builtin_amdgcn_mfma_f32_32x32x16_f16(a0, bfrag, cini, 0, 0, 0);
  f32x16 acc1 = __builtin_amdgcn_mfma_f32_32x32x16_f16(a1, bfrag, cini, 0, 0, 0);

  // ---- per-4-edge-block max (relu folded). lane holds blocks 8g+2q+h ----
  float bm[2][4];
#pragma unroll
  for (int q = 0; q < 4; q++) {
    bm[0][q] = fmaxf(fmaxf(acc0[4 * q], acc0[4 * q + 1]),
                     fmaxf(acc0[4 * q + 2], fmaxf(acc0[4 * q + 3], 0.f)));
    bm[1][q] = fmaxf(fmaxf(acc1[4 * q], acc1[4 * q + 1]),
                     fmaxf(acc1[4 * q + 2], fmaxf(acc1[4 * q + 3], 0.f)));
  }
  __builtin_amdgcn_s_setprio(0);

  // ---- run structure: heads only at 4-aligned lanes (padded scatter) ----
  int dp4 = __shfl_up(d, 4, 64);
  bool isHead = ((lane & 3) == 0) && (lane == 0 || d != dp4);
  unsigned long long hm = __ballot(isHead);

  unsigned long long rem = hm;
  while (rem) {
    int a = (int)__builtin_ctzll(rem);
    rem &= rem - 1;
    int b = rem ? (int)__builtin_ctzll(rem) : 64;
    int rd = __shfl(d, a, 64);
    int A = a >> 2, B = b >> 2;   // block range of this run
    float mx = 0.f;
#pragma unroll
    for (int g = 0; g < 2; g++) {
#pragma unroll
      for (int q = 0; q < 4; q++) {
        int blk = 8 * g + 2 * q + h;
        bool in = (blk >= A) && (blk < B);
        mx = fmaxf(mx, in ? bm[g][q] : 0.f);
      }
    }
    mx = fmaxf(mx, __shfl_xor(mx, 32, 64));
    if (lane < 32 && rd < N) {
      unsigned int bits = __float_as_uint(mx);
      atomicMax(agg32 + (size_t)rd * 32 + col, (tag << 30) | (bits >> 1));
    }
  }
}

// node-parallel: read agg row, TAG-decode (no zeroing pass), node MLP.
__global__ __launch_bounds__(256) void node_kernel(
    const float* __restrict__ x, const float* __restrict__ cin,
    float* __restrict__ cout, uint2* __restrict__ xpk,
    float* __restrict__ outFinal, const unsigned int* __restrict__ agg32,
    const float* __restrict__ wg, unsigned int tag, int n) {
  int nid = blockIdx.x * blockDim.x + threadIdx.x;
  if (nid >= n) return;
  const uint4* ap = (const uint4*)(agg32 + (size_t)nid * 32);
  uint4 q[8];
#pragma unroll
  for (int i = 0; i < 8; i++) q[i] = ap[i];
  float av[32];
#pragma unroll
  for (int i = 0; i < 8; i++) {
    unsigned int w[4] = {q[i].x, q[i].y, q[i].z, q[i].w};
#pragma unroll
    for (int j = 0; j < 4; j++) {
      unsigned int u = ((w[j] >> 30) == tag) ? ((w[j] & 0x3FFFFFFFu) << 1) : 0u;
      av[4 * i + j] = __uint_as_float(u);
    }
  }
  float x0 = x[3 * nid], x1 = x[3 * nid + 1];
  float x2 = cin ? cin[nid] : x[3 * nid + 2];
  float h[16];
#pragma unroll
  for (int o = 0; o < 16; o++) {
    float sa = wg[1200 + o];
    sa = fmaf(wg[640 + o * 35 + 0], x0, sa);
    sa = fmaf(wg[640 + o * 35 + 1], x1, sa);
    sa = fmaf(wg[640 + o * 35 + 2], x2, sa);
#pragma unroll
    for (int k = 0; k < 32; k++) sa = fmaf(wg[640 + o * 35 + 3 + k], av[k], sa);
    h[o] = fmaxf(sa, 0.f);
  }
  float z4 = wg[1232];
#pragma unroll
  for (int k = 0; k < 16; k++) z4 = fmaf(wg[1216 + k], h[k], z4);
  float comb = 1.f / (1.f + expf(-z4));
  cout[nid] = comb;
  ((unsigned int*)xpk)[2 * nid + 1] = h2u(__builtin_amdgcn_cvt_pkrtz(comb, 0.f));
  if (outFinal) {
    outFinal[3 * nid] = x0;
    outFinal[3 * nid + 1] = x1;
    outFinal[3 * nid + 2] = comb;
  }
}

extern "C" void kernel_launch(void* const* d_in, const int* in_sizes, int n_in,
                              void* d_out, int out_size, void* d_ws, size_t ws_size,
                              hipStream_t stream) {
  const float* x = (const float*)d_in[0];
  const float* ea = (const float*)d_in[1];
  const int* eidx = (const int*)d_in[2];
  const int N = in_sizes[0] / 3;
  const int E = in_sizes[1] / 2;
  const int* src = eidx;
  const int* dst = eidx + E;
  const int NBUCK = (N + 255) >> 8;  // dst buckets, 256 nodes each
  const int EP = E + 3 * N;          // padded-edge upper bound (actual in *etot)

  // ---- workspace carve-up ----
  char* p = (char*)d_ws;
  size_t off = 0;
  auto alloc = [&](size_t bytes) -> char* {
    char* r = p + off;
    off = (off + bytes + 255) & ~(size_t)255;
    return r;
  };
  float* wbuf = (float*)alloc((size_t)(PKOFS + PKTOT) * 4);
  int* bucketOff = (int*)alloc(((size_t)NBUCK + 1) * 4);
  int* bucketCur = (int*)alloc((size_t)NBUCK * 4);
  int* etot = (int*)alloc(4);
  uint2* se8 = (uint2*)alloc((size_t)EP * 8);            // {src, ea} per edge
  unsigned int* d4 = (unsigned int*)alloc(((size_t)(EP + 3) / 4 + 1) * 4);
  // agg32/xpk OUTSIDE the union: bhist initializes them while brec8 is live.
  unsigned int* agg32 = (unsigned int*)alloc(((size_t)N + 1) * 32 * 4);
  uint2* xpk = (uint2*)alloc((size_t)N * 8);
  // UNION region: build-phase brec8 (8B/edge) aliased with iteration-phase
  // bufA/bufB (brec8 dead after scat).
  char* uni = alloc((size_t)E * 8);
  uint2* brec8 = (uint2*)uni;
  float* bufA = (float*)uni;
  float* bufB = (float*)(uni + (((size_t)N * 4 + 255) & ~(size_t)255));
  (void)ws_size;

  PrepArgs pa;
  for (int l = 0; l < 4; l++) {
    pa.wmu[l] = (const float*)d_in[3 + 6 * l + 0];
    pa.wrho[l] = (const float*)d_in[3 + 6 * l + 1];
    pa.bmu[l] = (const float*)d_in[3 + 6 * l + 2];
    pa.brho[l] = (const float*)d_in[3 + 6 * l + 3];
    pa.epsw[l] = (const float*)d_in[3 + 6 * l + 4];
    pa.epsb[l] = (const float*)d_in[3 + 6 * l + 5];
  }
  pa.out = wbuf;
  pa.bucketCur = bucketCur;
  pa.etot = etot;
  pa.nbuck = NBUCK;

  const int TB = 256;
  auto blocks = [&](int n) { return dim3((n + TB - 1) / TB); };

  prep_all_kernel<<<dim3(1), dim3(1024), 0, stream>>>(pa);
  {
    int gb = (E + 8191) / 8192;
    int gn = (N + 255) / 256;
    int g = gb > gn ? gb : gn;
    bhist_kernel<<<dim3(g), dim3(1024), 0, stream>>>(dst, bucketCur, x, xpk, agg32,
                                                     E, N, NBUCK);
  }
  scanBk_kernel<<<dim3(1), dim3(1024), 0, stream>>>(bucketCur, bucketOff, NBUCK);
  part_kernel<<<dim3((E + 8191) / 8192), dim3(1024), 0, stream>>>(
      src, dst, (const float2*)ea, bucketCur, brec8, E, NBUCK);
  scat_kernel<<<dim3(NBUCK), dim3(1024), 0, stream>>>(brec8, bucketOff, etot, se8, d4, N);

  float* outp = (float*)d_out;
  const int ebp = (EP + 255) / 256;
  // iter 1
  edge_kernel<<<dim3(ebp), dim3(TB), 0, stream>>>(xpk, se8, d4, agg32, wbuf, etot, 1u, N);
  node_kernel<<<blocks(N), dim3(TB), 0, stream>>>(x, nullptr, bufA, xpk, nullptr,
                                                  agg32, wbuf, 1u, N);
  // iter 2
  edge_kernel<<<dim3(ebp), dim3(TB), 0, stream>>>(xpk, se8, d4, agg32, wbuf, etot, 2u, N);
  node_kernel<<<blocks(N), dim3(TB), 0, stream>>>(x, bufA, bufB, xpk, nullptr,
                                                  agg32, wbuf, 2u, N);
  // iter 3
  edge_kernel<<<dim3(ebp), dim3(TB), 0, stream>>>(xpk, se8, d4, agg32, wbuf, etot, 3u, N);
  node_kernel<<<blocks(N), dim3(TB), 0, stream>>>(x, bufB, bufA, xpk, outp,
                                                  agg32, wbuf, 3u, N);
}